// Round 2
// baseline (3721.205 us; speedup 1.0000x reference)
//
#include <hip/hip_runtime.h>
#include <math.h>

#define NPTS 2048
#define LDM 17           // padded LDS row stride (16+1) to break bank conflicts
#define NSWEEP 10        // Jacobi sweeps (parallel tournament order)
#define NS_ITERS 9       // Newton-Schulz iterations for inv-sqrt

// ---------------------------------------------------------------------------
// Wave-cooperative 16x16 matmul: C = A*B. Lane l computes row (l&15),
// columns [ (l>>4)*4 .. +3 ]. Caller handles barriers.
// ---------------------------------------------------------------------------
__device__ __forceinline__ void matmul16(const float* A, const float* B, float* C, int lane){
    int i  = lane & 15;
    int j0 = (lane >> 4) * 4;
    float c0 = 0.f, c1 = 0.f, c2 = 0.f, c3 = 0.f;
#pragma unroll
    for (int k = 0; k < 16; ++k){
        float a = A[i*LDM + k];
        c0 = fmaf(a, B[k*LDM + j0 + 0], c0);
        c1 = fmaf(a, B[k*LDM + j0 + 1], c1);
        c2 = fmaf(a, B[k*LDM + j0 + 2], c2);
        c3 = fmaf(a, B[k*LDM + j0 + 3], c3);
    }
    C[i*LDM + j0 + 0] = c0;
    C[i*LDM + j0 + 1] = c1;
    C[i*LDM + j0 + 2] = c2;
    C[i*LDM + j0 + 3] = c3;
}

// Tournament (circle-method) pairing: round r in [0,15), pair k in [0,8)
__device__ __forceinline__ void jpair(int r, int k, int& pI, int& qI){
    if (k == 0){ pI = r; qI = 15; }
    else {
        int a = (r + k) % 15;
        int b = (r + 15 - k) % 15;
        pI = a < b ? a : b;
        qI = a < b ? b : a;
    }
}

// ---------------------------------------------------------------------------
// Kernel 1: S_n = Y_n^{-1/2} for all n, via coupled Newton-Schulz.
// One wave per point, 4 points per block.
// ---------------------------------------------------------------------------
__global__ __launch_bounds__(256) void precompute_invsqrt(const float* __restrict__ embeds,
                                                          float* __restrict__ Sout){
    __shared__ float buf[4][5][16*LDM];
    const int w    = threadIdx.x >> 6;
    const int lane = threadIdx.x & 63;
    const int n    = blockIdx.x * 4 + w;   // grid = 512 -> n < 2048 always

    float* Bm = buf[w][0];
    float* Zm = buf[w][1];
    float* Tm = buf[w][2];
    float* B2 = buf[w][3];
    float* Z2 = buf[w][4];

    const float* gY = embeds + (size_t)n * 512 + 256;   // Y part of point n

    // load Y, accumulate Frobenius norm^2
    float ss = 0.f;
#pragma unroll
    for (int t = 0; t < 4; ++t){
        int e = lane + t*64;
        float v = gY[e];
        Bm[(e >> 4)*LDM + (e & 15)] = v;
        ss += v*v;
    }
#pragma unroll
    for (int m = 1; m < 64; m <<= 1) ss += __shfl_xor(ss, m);
    float f    = sqrtf(ss);
    float invf = 1.0f / f;
    __syncthreads();

    // B0 = Y/f (spectrum in (0,1]) ; Z0 = I
#pragma unroll
    for (int t = 0; t < 4; ++t){
        int e = lane + t*64; int i = e >> 4, j = e & 15;
        Bm[i*LDM + j] *= invf;
        Zm[i*LDM + j]  = (i == j) ? 1.f : 0.f;
    }
    __syncthreads();

    for (int it = 0; it < NS_ITERS; ++it){
        matmul16(Zm, Bm, Tm, lane);          // Tm = Z*B
        __syncthreads();
#pragma unroll
        for (int t = 0; t < 4; ++t){
            int e = lane + t*64; int i = e >> 4, j = e & 15;
            float v = -0.5f * Tm[i*LDM + j] + ((i == j) ? 1.5f : 0.f);
            Tm[i*LDM + j] = v;               // T = (3I - Z*B)/2
        }
        __syncthreads();
        matmul16(Bm, Tm, B2, lane);          // B <- B*T
        matmul16(Tm, Zm, Z2, lane);          // Z <- T*Z
        __syncthreads();
        float* tp;
        tp = Bm; Bm = B2; B2 = tp;
        tp = Zm; Zm = Z2; Z2 = tp;
    }

    // Z -> (Y/f)^{-1/2} = sqrt(f) * Y^{-1/2}  =>  S = Z / sqrt(f)
    float sc = rsqrtf(f);
    float* out = Sout + (size_t)n * 256;
#pragma unroll
    for (int t = 0; t < 4; ++t){
        int e = lane + t*64; int i = e >> 4, j = e & 15;
        out[e] = Zm[i*LDM + j] * sc;
    }
}

// ---------------------------------------------------------------------------
// Kernel 2: per-pair Siegel distance -> loss term. One wave per pair.
// ---------------------------------------------------------------------------
__global__ __launch_bounds__(256) void siegel_pairs(const float* __restrict__ embeds,
                                                    const float* __restrict__ gdist,
                                                    const int*   __restrict__ src,
                                                    const int*   __restrict__ dst,
                                                    const float* __restrict__ S,
                                                    float* __restrict__ partials,
                                                    int P){
    __shared__ float buf[4][5][16*LDM];
    __shared__ float rot[4][8][4];
    __shared__ float ldi[4][16];
    __shared__ float wterm[4];

    const int w    = threadIdx.x >> 6;
    const int lane = threadIdx.x & 63;
    const int p    = blockIdx.x * 4 + w;
    const bool valid = (p < P);
    const int pp = valid ? p : 0;
    const int a = src[pp];
    const int b = dst[pp];

    float* M0 = buf[w][0];   // S2
    float* M1 = buf[w][1];   // Xd -> X3
    float* M2 = buf[w][2];   // Y1 -> Y3 -> L (Cholesky)
    float* M3 = buf[w][3];   // T -> G -> CR
    float* M4 = buf[w][4];   // T -> E -> CI

    const float* e1 = embeds + (size_t)a * 512;
    const float* e2 = embeds + (size_t)b * 512;
    const float* S2 = S + (size_t)b * 256;

#pragma unroll
    for (int t = 0; t < 4; ++t){
        int e = lane + t*64; int i = e >> 4, j = e & 15;
        M0[i*LDM + j] = S2[e];
        M1[i*LDM + j] = e1[e] - e2[e];      // Xd = X1 - X2
        M2[i*LDM + j] = e1[256 + e];        // Y1
    }
    __syncthreads();

    matmul16(M0, M1, M3, lane);             // M3 = S*Xd
    matmul16(M0, M2, M4, lane);             // M4 = S*Y1
    __syncthreads();
    matmul16(M3, M0, M1, lane);             // M1 = X3 = S*Xd*S
    matmul16(M4, M0, M2, lane);             // M2 = Y3 = S*Y1*S
    __syncthreads();

    // M3 = G = X3^2 + Y3^2 + I ; M4 = E = Y3*X3 - X3*Y3   (H = G + iE)
    {
        int i = lane & 15, j0 = (lane >> 4) * 4;
        float g0=0,g1=0,g2=0,g3=0, q0=0,q1=0,q2=0,q3=0;
#pragma unroll
        for (int k = 0; k < 16; ++k){
            float x = M1[i*LDM + k];
            float y = M2[i*LDM + k];
            float xk0 = M1[k*LDM + j0+0], yk0 = M2[k*LDM + j0+0];
            float xk1 = M1[k*LDM + j0+1], yk1 = M2[k*LDM + j0+1];
            float xk2 = M1[k*LDM + j0+2], yk2 = M2[k*LDM + j0+2];
            float xk3 = M1[k*LDM + j0+3], yk3 = M2[k*LDM + j0+3];
            g0 += x*xk0 + y*yk0;  q0 += y*xk0 - x*yk0;
            g1 += x*xk1 + y*yk1;  q1 += y*xk1 - x*yk1;
            g2 += x*xk2 + y*yk2;  q2 += y*xk2 - x*yk2;
            g3 += x*xk3 + y*yk3;  q3 += y*xk3 - x*yk3;
        }
        M3[i*LDM + j0+0] = g0 + ((i == j0+0) ? 1.f : 0.f);
        M3[i*LDM + j0+1] = g1 + ((i == j0+1) ? 1.f : 0.f);
        M3[i*LDM + j0+2] = g2 + ((i == j0+2) ? 1.f : 0.f);
        M3[i*LDM + j0+3] = g3 + ((i == j0+3) ? 1.f : 0.f);
        M4[i*LDM + j0+0] = q0;
        M4[i*LDM + j0+1] = q1;
        M4[i*LDM + j0+2] = q2;
        M4[i*LDM + j0+3] = q3;
    }
    __syncthreads();

    // Cholesky of Y3 (M2), lower triangle, L(k,k) inverse into ldi
    for (int k = 0; k < 16; ++k){
        float akk = M2[k*LDM + k];            // broadcast read
        float rs  = rsqrtf(akk);
        if (lane == 0) ldi[w][k] = rs;
        if (lane > k && lane < 16) M2[lane*LDM + k] *= rs;
        __syncthreads();
        {
            int i = lane & 15, jg = lane >> 4;
            if (i > k){
                float lik = M2[i*LDM + k];
                for (int j = k + 1 + jg; j <= i; j += 4)
                    M2[i*LDM + j] -= lik * M2[j*LDM + k];
            }
        }
        __syncthreads();
    }

    // Forward solve on columns (in place):  Z = L^{-1} H   (real & imag planes)
    {
        float* Mb = (lane < 16) ? M3 : ((lane < 32) ? M4 : (float*)0);
        int col = lane & 15;
        if (Mb){
            float z[16];
#pragma unroll
            for (int i = 0; i < 16; ++i){
                float v = Mb[i*LDM + col];
#pragma unroll
                for (int m = 0; m < i; ++m) v -= M2[i*LDM + m] * z[m];
                z[i] = v * ldi[w][i];
            }
#pragma unroll
            for (int i = 0; i < 16; ++i) Mb[i*LDM + col] = z[i];
        }
    }
    __syncthreads();

    // Row solve (in place):  C = Z L^{-T}
    {
        float* Mb = (lane < 16) ? M3 : ((lane < 32) ? M4 : (float*)0);
        int r = lane & 15;
        if (Mb){
            float z[16];
#pragma unroll
            for (int j = 0; j < 16; ++j){
                float v = Mb[r*LDM + j];
#pragma unroll
                for (int m = 0; m < j; ++m) v -= M2[j*LDM + m] * z[m];
                z[j] = v * ldi[w][j];
            }
#pragma unroll
            for (int j = 0; j < 16; ++j) Mb[r*LDM + j] = z[j];
        }
    }
    __syncthreads();

    // Hermitian-ize C: CR <- (CR+CR^T)/2, CI <- (CI-CI^T)/2 (kills fp asymmetry)
    {
        int i = lane & 15, j0 = (lane >> 4) * 4;
        float ar[4], at[4], br[4], bt[4];
#pragma unroll
        for (int t = 0; t < 4; ++t){
            ar[t] = M3[i*LDM + j0+t];  at[t] = M3[(j0+t)*LDM + i];
            br[t] = M4[i*LDM + j0+t];  bt[t] = M4[(j0+t)*LDM + i];
        }
        __syncthreads();
#pragma unroll
        for (int t = 0; t < 4; ++t){
            M3[i*LDM + j0+t] = 0.5f*(ar[t] + at[t]);
            M4[i*LDM + j0+t] = 0.5f*(br[t] - bt[t]);
        }
    }
    __syncthreads();

    // Jacobi (parallel tournament order), eigenvalues only
#pragma unroll 1
    for (int sweep = 0; sweep < NSWEEP; ++sweep){
#pragma unroll 1
        for (int r = 0; r < 15; ++r){
            if (lane < 8){
                int pI, qI; jpair(r, lane, pI, qI);
                float app = M3[pI*LDM + pI];
                float aqq = M3[qI*LDM + qI];
                float br  = M3[pI*LDM + qI];
                float bi  = M4[pI*LDM + qI];
                float n2  = br*br + bi*bi;
                float c, s, wr, wi;
                if (n2 < 1e-28f){ c = 1.f; s = 0.f; wr = 1.f; wi = 0.f; }
                else {
                    float nb  = sqrtf(n2);
                    float inb = 1.0f / nb;
                    wr = br * inb; wi = bi * inb;
                    float tau = (aqq - app) * (0.5f * inb);
                    float tt  = ((tau >= 0.f) ? 1.f : -1.f) / (fabsf(tau) + sqrtf(1.f + tau*tau));
                    c = rsqrtf(1.f + tt*tt);
                    s = tt * c;
                }
                rot[w][lane][0] = c;  rot[w][lane][1] = s;
                rot[w][lane][2] = wr; rot[w][lane][3] = wi;
            }
            __syncthreads();
            // row phase: A <- R^H A   (tasks disjoint per element)
#pragma unroll
            for (int tt2 = 0; tt2 < 2; ++tt2){
                int t = lane + tt2*64;
                int k = t >> 4, j = t & 15;
                int pI, qI; jpair(r, k, pI, qI);
                float c = rot[w][k][0], s = rot[w][k][1];
                float wr = rot[w][k][2], wi = rot[w][k][3];
                float apr = M3[pI*LDM + j], api = M4[pI*LDM + j];
                float aqr = M3[qI*LDM + j], aqi = M4[qI*LDM + j];
                float wqr = wr*aqr - wi*aqi;      // w * aq
                float wqi = wr*aqi + wi*aqr;
                M3[pI*LDM + j] = c*apr - s*wqr;
                M4[pI*LDM + j] = c*api - s*wqi;
                M3[qI*LDM + j] = s*apr + c*wqr;
                M4[qI*LDM + j] = s*api + c*wqi;
            }
            __syncthreads();
            // column phase: A <- A R
#pragma unroll
            for (int tt2 = 0; tt2 < 2; ++tt2){
                int t = lane + tt2*64;
                int k = t >> 4, i = t & 15;
                int pI, qI; jpair(r, k, pI, qI);
                float c = rot[w][k][0], s = rot[w][k][1];
                float wr = rot[w][k][2], wi = rot[w][k][3];
                float apr = M3[i*LDM + pI], api = M4[i*LDM + pI];
                float aqr = M3[i*LDM + qI], aqi = M4[i*LDM + qI];
                float wqr = wr*aqr + wi*aqi;      // conj(w) * aq
                float wqi = wr*aqi - wi*aqr;
                M3[i*LDM + pI] = c*apr - s*wqr;
                M4[i*LDM + pI] = c*api - s*wqi;
                M3[i*LDM + qI] = s*apr + c*wqr;
                M4[i*LDM + qI] = s*api + c*wqi;
            }
            __syncthreads();
        }
    }

    // eigenvalues mu on diag(CR) -> lambda -> v -> sum v^2 -> loss term
    float t2 = 0.f;
    if (lane < 16){
        float mu  = M3[lane*LDM + lane];
        float lam = (mu - 2.f) / (mu + 2.f);
        const float lo = 1e-6f;
        const float hi = (1.f - 1e-6f) * (1.f - 1e-6f);
        lam = fminf(fmaxf(lam, lo), hi);
        float sv = sqrtf(lam);
        float v  = logf((1.f + sv) / (1.f - sv));
        t2 = v * v;
    }
#pragma unroll
    for (int m = 1; m < 16; m <<= 1) t2 += __shfl_xor(t2, m);
    if (lane == 0){
        float gd   = gdist[(size_t)a * NPTS + b];
        float term = fabsf(t2 / (gd * gd) - 1.f);
        wterm[w] = valid ? term : 0.f;
    }
    __syncthreads();
    if (threadIdx.x == 0)
        partials[blockIdx.x] = wterm[0] + wterm[1] + wterm[2] + wterm[3];
}

// ---------------------------------------------------------------------------
// Kernel 3: final reduction (double accumulation), single block
// ---------------------------------------------------------------------------
__global__ __launch_bounds__(256) void reduce_partials(const float* __restrict__ partials,
                                                       int n, float* __restrict__ out){
    __shared__ double sd[256];
    double s = 0.0;
    for (int i = threadIdx.x; i < n; i += 256) s += (double)partials[i];
    sd[threadIdx.x] = s;
    __syncthreads();
    for (int st = 128; st > 0; st >>= 1){
        if (threadIdx.x < st) sd[threadIdx.x] += sd[threadIdx.x + st];
        __syncthreads();
    }
    if (threadIdx.x == 0) out[0] = (float)sd[0];
}

extern "C" void kernel_launch(void* const* d_in, const int* in_sizes, int n_in,
                              void* d_out, int out_size, void* d_ws, size_t ws_size,
                              hipStream_t stream){
    const float* embeds = (const float*)d_in[0];
    const float* gdist  = (const float*)d_in[1];
    const int*   src    = (const int*)d_in[2];
    const int*   dst    = (const int*)d_in[3];
    const int P = in_sizes[2];

    float* S        = (float*)d_ws;                 // 2048*256 floats = 2 MB
    float* partials = S + (size_t)NPTS * 256;

    const int nb = (P + 3) / 4;

    precompute_invsqrt<<<dim3(NPTS/4), dim3(256), 0, stream>>>(embeds, S);
    siegel_pairs<<<dim3(nb), dim3(256), 0, stream>>>(embeds, gdist, src, dst, S, partials, P);
    reduce_partials<<<dim3(1), dim3(256), 0, stream>>>(partials, nb, (float*)d_out);
}

// Round 3
// 2651.672 us; speedup vs baseline: 1.4033x; 1.4033x over previous
//
#include <hip/hip_runtime.h>
#include <math.h>

#define NPTS 2048
#define LDM 17           // padded LDS row stride for the dense-matmul phase
#define NSWEEP 10        // Jacobi sweeps (parallel tournament order)
#define NS_ITERS 9       // Newton-Schulz iterations for inv-sqrt
#define SWZ(i,j) (((i)<<4) + ((((i)+(j))&15)))   // conflict-free Jacobi layout

// Wave-private LDS sync: writes committed (lgkmcnt) + compiler fence.
// Valid because each wave only ever reads LDS written by ITSELF between syncs.
__device__ __forceinline__ void wave_sync(){
    asm volatile("s_waitcnt lgkmcnt(0)" ::: "memory");
    __builtin_amdgcn_sched_barrier(0);
}

// ---------------------------------------------------------------------------
// Wave-cooperative 16x16 matmul: C = A*B. Lane l computes row (l&15),
// columns [ (l>>4)*4 .. +3 ]. Caller handles syncs.
// ---------------------------------------------------------------------------
__device__ __forceinline__ void matmul16(const float* A, const float* B, float* C, int lane){
    int i  = lane & 15;
    int j0 = (lane >> 4) * 4;
    float c0 = 0.f, c1 = 0.f, c2 = 0.f, c3 = 0.f;
#pragma unroll
    for (int k = 0; k < 16; ++k){
        float a = A[i*LDM + k];
        c0 = fmaf(a, B[k*LDM + j0 + 0], c0);
        c1 = fmaf(a, B[k*LDM + j0 + 1], c1);
        c2 = fmaf(a, B[k*LDM + j0 + 2], c2);
        c3 = fmaf(a, B[k*LDM + j0 + 3], c3);
    }
    C[i*LDM + j0 + 0] = c0;
    C[i*LDM + j0 + 1] = c1;
    C[i*LDM + j0 + 2] = c2;
    C[i*LDM + j0 + 3] = c3;
}

// Tournament (circle-method) pairing: round r in [0,15), pair k in [0,8)
__device__ __forceinline__ void jpair(int r, int k, int& pI, int& qI){
    if (k == 0){ pI = r; qI = 15; }
    else {
        int a = (r + k) % 15;
        int b = (r + 15 - k) % 15;
        pI = a < b ? a : b;
        qI = a < b ? b : a;
    }
}

// ---------------------------------------------------------------------------
// Kernel 1: S_n = Y_n^{-1/2} for all n, via coupled Newton-Schulz.
// One wave per point, 4 points per block. (~1% of runtime — unchanged.)
// ---------------------------------------------------------------------------
__global__ __launch_bounds__(256) void precompute_invsqrt(const float* __restrict__ embeds,
                                                          float* __restrict__ Sout){
    __shared__ float buf[4][5][16*LDM];
    const int w    = threadIdx.x >> 6;
    const int lane = threadIdx.x & 63;
    const int n    = blockIdx.x * 4 + w;

    float* Bm = buf[w][0];
    float* Zm = buf[w][1];
    float* Tm = buf[w][2];
    float* B2 = buf[w][3];
    float* Z2 = buf[w][4];

    const float* gY = embeds + (size_t)n * 512 + 256;

    float ss = 0.f;
#pragma unroll
    for (int t = 0; t < 4; ++t){
        int e = lane + t*64;
        float v = gY[e];
        Bm[(e >> 4)*LDM + (e & 15)] = v;
        ss += v*v;
    }
#pragma unroll
    for (int m = 1; m < 64; m <<= 1) ss += __shfl_xor(ss, m);
    float f    = sqrtf(ss);
    float invf = 1.0f / f;
    __syncthreads();

#pragma unroll
    for (int t = 0; t < 4; ++t){
        int e = lane + t*64; int i = e >> 4, j = e & 15;
        Bm[i*LDM + j] *= invf;
        Zm[i*LDM + j]  = (i == j) ? 1.f : 0.f;
    }
    __syncthreads();

    for (int it = 0; it < NS_ITERS; ++it){
        matmul16(Zm, Bm, Tm, lane);
        __syncthreads();
#pragma unroll
        for (int t = 0; t < 4; ++t){
            int e = lane + t*64; int i = e >> 4, j = e & 15;
            float v = -0.5f * Tm[i*LDM + j] + ((i == j) ? 1.5f : 0.f);
            Tm[i*LDM + j] = v;
        }
        __syncthreads();
        matmul16(Bm, Tm, B2, lane);
        matmul16(Tm, Zm, Z2, lane);
        __syncthreads();
        float* tp;
        tp = Bm; Bm = B2; B2 = tp;
        tp = Zm; Zm = Z2; Z2 = tp;
    }

    float sc = rsqrtf(f);
    float* out = Sout + (size_t)n * 256;
#pragma unroll
    for (int t = 0; t < 4; ++t){
        int e = lane + t*64; int i = e >> 4, j = e & 15;
        out[e] = Zm[i*LDM + j] * sc;
    }
}

// ---------------------------------------------------------------------------
// Kernel 2: per-pair Siegel distance -> loss term. One wave per pair,
// fully wave-private (no block barriers in the hot path).
// ---------------------------------------------------------------------------
__global__ __launch_bounds__(256) void siegel_pairs(const float* __restrict__ embeds,
                                                    const float* __restrict__ gdist,
                                                    const int*   __restrict__ src,
                                                    const int*   __restrict__ dst,
                                                    const float* __restrict__ S,
                                                    float* __restrict__ partials,
                                                    int P){
    __shared__ float  buf[4][4][16*LDM];   // 4 matrices per wave
    __shared__ float4 rotv[4][8];
    __shared__ ushort ptab[120];           // tournament pair table (block-shared, RO)
    __shared__ float  wterm[4];

    const int w    = threadIdx.x >> 6;
    const int lane = threadIdx.x & 63;

    if (threadIdx.x < 120){
        int r = threadIdx.x >> 3, k = threadIdx.x & 7;
        int pI, qI; jpair(r, k, pI, qI);
        ptab[threadIdx.x] = (ushort)(pI | (qI << 8));
    }
    __syncthreads();                        // ptab ready for all waves

    const int p = blockIdx.x * 4 + w;
    const bool valid = (p < P);
    const int pp = valid ? p : 0;
    const int a = src[pp];
    const int b = dst[pp];

    float* M0 = buf[w][0];   // S2 -> E(CI, ldm layout)
    float* M1 = buf[w][1];   // Xd -> X3 -> (CRCI low half)
    float* M2 = buf[w][2];   // Y1 -> Y3 -> L -> (CRCI high half)
    float* M3 = buf[w][3];   // T1/T2 -> G(CR, ldm layout)
    float2* CRCI = (float2*)M1;  // 256 float2 spanning M1+M2 (dead by then)

    const float* e1 = embeds + (size_t)a * 512;
    const float* e2 = embeds + (size_t)b * 512;
    const float* S2 = S + (size_t)b * 256;

#pragma unroll
    for (int t = 0; t < 4; ++t){
        int e = lane + t*64; int i = e >> 4, j = e & 15;
        M0[i*LDM + j] = S2[e];
        M1[i*LDM + j] = e1[e] - e2[e];      // Xd = X1 - X2
        M2[i*LDM + j] = e1[256 + e];        // Y1
    }
    wave_sync();

    matmul16(M0, M1, M3, lane);             // T1 = S*Xd
    wave_sync();
    matmul16(M3, M0, M1, lane);             // X3 = T1*S   (over Xd)
    wave_sync();
    matmul16(M0, M2, M3, lane);             // T2 = S*Y1   (over T1)
    wave_sync();
    matmul16(M3, M0, M2, lane);             // Y3 = T2*S   (over Y1)
    wave_sync();

    // G = X3^2 + Y3^2 + I -> M3 ;  E = Y3*X3 - X3*Y3 -> M0   (H = G + iE)
    {
        int i = lane & 15, j0 = (lane >> 4) * 4;
        float g0=0,g1=0,g2=0,g3=0, q0=0,q1=0,q2=0,q3=0;
#pragma unroll
        for (int k = 0; k < 16; ++k){
            float x = M1[i*LDM + k];
            float y = M2[i*LDM + k];
            float xk0 = M1[k*LDM + j0+0], yk0 = M2[k*LDM + j0+0];
            float xk1 = M1[k*LDM + j0+1], yk1 = M2[k*LDM + j0+1];
            float xk2 = M1[k*LDM + j0+2], yk2 = M2[k*LDM + j0+2];
            float xk3 = M1[k*LDM + j0+3], yk3 = M2[k*LDM + j0+3];
            g0 += x*xk0 + y*yk0;  q0 += y*xk0 - x*yk0;
            g1 += x*xk1 + y*yk1;  q1 += y*xk1 - x*yk1;
            g2 += x*xk2 + y*yk2;  q2 += y*xk2 - x*yk2;
            g3 += x*xk3 + y*yk3;  q3 += y*xk3 - x*yk3;
        }
        M3[i*LDM + j0+0] = g0 + ((i == j0+0) ? 1.f : 0.f);
        M3[i*LDM + j0+1] = g1 + ((i == j0+1) ? 1.f : 0.f);
        M3[i*LDM + j0+2] = g2 + ((i == j0+2) ? 1.f : 0.f);
        M3[i*LDM + j0+3] = g3 + ((i == j0+3) ? 1.f : 0.f);
        M0[i*LDM + j0+0] = q0;
        M0[i*LDM + j0+1] = q1;
        M0[i*LDM + j0+2] = q2;
        M0[i*LDM + j0+3] = q3;
    }
    wave_sync();

    // Cholesky of Y3 (M2): L in lower triangle, 1/L_kk stored ON the diagonal
    for (int k = 0; k < 16; ++k){
        float akk = M2[k*LDM + k];           // read-before-overwrite: in-order DS
        float rs  = rsqrtf(akk);
        if (lane == 0) M2[k*LDM + k] = rs;
        if (lane > k && lane < 16) M2[lane*LDM + k] *= rs;
        wave_sync();
        int i = lane & 15, jg = lane >> 4;
        if (i > k){
            float lik = M2[i*LDM + k];
            for (int j = k + 1 + jg; j <= i; j += 4)
                M2[i*LDM + j] -= lik * M2[j*LDM + k];
        }
        wave_sync();
    }

    // Forward solve  Z = L^{-1} H : lanes 0-15 on G (M3), 16-31 on E (M0)
    {
        float* Mb = (lane < 16) ? M3 : ((lane < 32) ? M0 : (float*)0);
        int col = lane & 15;
        if (Mb){
            float z[16];
#pragma unroll
            for (int i = 0; i < 16; ++i){
                float v = Mb[i*LDM + col];
#pragma unroll
                for (int m = 0; m < i; ++m) v -= M2[i*LDM + m] * z[m];
                z[i] = v * M2[i*LDM + i];
            }
#pragma unroll
            for (int i = 0; i < 16; ++i) Mb[i*LDM + col] = z[i];
        }
    }
    wave_sync();

    // Row solve  C = Z L^{-T}
    {
        float* Mb = (lane < 16) ? M3 : ((lane < 32) ? M0 : (float*)0);
        int r = lane & 15;
        if (Mb){
            float z[16];
#pragma unroll
            for (int j = 0; j < 16; ++j){
                float v = Mb[r*LDM + j];
#pragma unroll
                for (int m = 0; m < j; ++m) v -= M2[j*LDM + m] * z[m];
                z[j] = v * M2[j*LDM + j];
            }
#pragma unroll
            for (int j = 0; j < 16; ++j) Mb[r*LDM + j] = z[j];
        }
    }
    wave_sync();

    // Hermitianize into interleaved, swizzled complex storage (over M1+M2)
    {
        int i = lane & 15, jg = lane >> 4;
#pragma unroll
        for (int t = 0; t < 4; ++t){
            int j = jg + 4*t;
            float cr = 0.5f*(M3[i*LDM + j] + M3[j*LDM + i]);
            float ci = 0.5f*(M0[i*LDM + j] - M0[j*LDM + i]);
            CRCI[SWZ(i,j)] = make_float2(cr, ci);
        }
    }
    wave_sync();

    // Jacobi (parallel tournament order), eigenvalues only — wave-private
#pragma unroll 1
    for (int sweep = 0; sweep < NSWEEP; ++sweep){
#pragma unroll 1
        for (int r = 0; r < 15; ++r){
            const ushort* pr = &ptab[r*8];
            if (lane < 8){
                int pq = pr[lane]; int pI = pq & 255, qI = pq >> 8;
                float app = CRCI[SWZ(pI,pI)].x;
                float aqq = CRCI[SWZ(qI,qI)].x;
                float2 bb = CRCI[SWZ(pI,qI)];
                float n2 = bb.x*bb.x + bb.y*bb.y;
                float c, s, wr, wi;
                if (n2 < 1e-28f){ c = 1.f; s = 0.f; wr = 1.f; wi = 0.f; }
                else {
                    float nb  = sqrtf(n2);
                    float inb = 1.0f / nb;
                    wr = bb.x * inb; wi = bb.y * inb;
                    float tau = (aqq - app) * (0.5f * inb);
                    float tt  = ((tau >= 0.f) ? 1.f : -1.f) / (fabsf(tau) + sqrtf(1.f + tau*tau));
                    c = rsqrtf(1.f + tt*tt);
                    s = tt * c;
                }
                rotv[w][lane] = make_float4(c, s, wr, wi);
            }
            wave_sync();
            // row phase: A <- R^H A  (8 disjoint row-pairs, 2 per lane)
#pragma unroll
            for (int h = 0; h < 2; ++h){
                int k = (lane >> 4) + 4*h;
                int j = lane & 15;
                int pq = pr[k]; int pI = pq & 255, qI = pq >> 8;
                float4 ro = rotv[w][k];
                int aP = SWZ(pI,j), aQ = SWZ(qI,j);
                float2 ap = CRCI[aP], aq = CRCI[aQ];
                float wqr = ro.z*aq.x - ro.w*aq.y;      // w * aq
                float wqi = ro.z*aq.y + ro.w*aq.x;
                CRCI[aP] = make_float2(ro.x*ap.x - ro.y*wqr, ro.x*ap.y - ro.y*wqi);
                CRCI[aQ] = make_float2(ro.y*ap.x + ro.x*wqr, ro.y*ap.y + ro.x*wqi);
            }
            wave_sync();
            // column phase: A <- A R
#pragma unroll
            for (int h = 0; h < 2; ++h){
                int k = (lane >> 4) + 4*h;
                int i = lane & 15;
                int pq = pr[k]; int pI = pq & 255, qI = pq >> 8;
                float4 ro = rotv[w][k];
                int aP = SWZ(i,pI), aQ = SWZ(i,qI);
                float2 ap = CRCI[aP], aq = CRCI[aQ];
                float wqr = ro.z*aq.x + ro.w*aq.y;      // conj(w) * aq
                float wqi = ro.z*aq.y - ro.w*aq.x;
                CRCI[aP] = make_float2(ro.x*ap.x - ro.y*wqr, ro.x*ap.y - ro.y*wqi);
                CRCI[aQ] = make_float2(ro.y*ap.x + ro.x*wqr, ro.y*ap.y + ro.x*wqi);
            }
            wave_sync();
        }
    }

    // eigenvalues mu on diag -> lambda -> v -> sum v^2 -> loss term
    float t2 = 0.f;
    if (lane < 16){
        float mu  = CRCI[SWZ(lane,lane)].x;
        float lam = (mu - 2.f) / (mu + 2.f);
        const float lo = 1e-6f;
        const float hi = (1.f - 1e-6f) * (1.f - 1e-6f);
        lam = fminf(fmaxf(lam, lo), hi);
        float sv = sqrtf(lam);
        float v  = logf((1.f + sv) / (1.f - sv));
        t2 = v * v;
    }
#pragma unroll
    for (int m = 1; m < 16; m <<= 1) t2 += __shfl_xor(t2, m);
    if (lane == 0){
        float gd   = gdist[(size_t)a * NPTS + b];
        float term = fabsf(t2 / (gd * gd) - 1.f);
        wterm[w] = valid ? term : 0.f;
    }
    __syncthreads();
    if (threadIdx.x == 0)
        partials[blockIdx.x] = wterm[0] + wterm[1] + wterm[2] + wterm[3];
}

// ---------------------------------------------------------------------------
// Kernel 3: final reduction (double accumulation), single block
// ---------------------------------------------------------------------------
__global__ __launch_bounds__(256) void reduce_partials(const float* __restrict__ partials,
                                                       int n, float* __restrict__ out){
    __shared__ double sd[256];
    double s = 0.0;
    for (int i = threadIdx.x; i < n; i += 256) s += (double)partials[i];
    sd[threadIdx.x] = s;
    __syncthreads();
    for (int st = 128; st > 0; st >>= 1){
        if (threadIdx.x < st) sd[threadIdx.x] += sd[threadIdx.x + st];
        __syncthreads();
    }
    if (threadIdx.x == 0) out[0] = (float)sd[0];
}

extern "C" void kernel_launch(void* const* d_in, const int* in_sizes, int n_in,
                              void* d_out, int out_size, void* d_ws, size_t ws_size,
                              hipStream_t stream){
    const float* embeds = (const float*)d_in[0];
    const float* gdist  = (const float*)d_in[1];
    const int*   src    = (const int*)d_in[2];
    const int*   dst    = (const int*)d_in[3];
    const int P = in_sizes[2];

    float* S        = (float*)d_ws;                 // 2048*256 floats = 2 MB
    float* partials = S + (size_t)NPTS * 256;

    const int nb = (P + 3) / 4;

    precompute_invsqrt<<<dim3(NPTS/4), dim3(256), 0, stream>>>(embeds, S);
    siegel_pairs<<<dim3(nb), dim3(256), 0, stream>>>(embeds, gdist, src, dst, S, partials, P);
    reduce_partials<<<dim3(1), dim3(256), 0, stream>>>(partials, nb, (float*)d_out);
}

// Round 4
// 2225.994 us; speedup vs baseline: 1.6717x; 1.1912x over previous
//
#include <hip/hip_runtime.h>
#include <math.h>

#define NPTS 2048
#define LDM 17           // padded LDS row stride for the dense-matmul phase
#define NSWEEP 8         // Jacobi sweeps (fp32 floor reached ~sweep 6; 2 margin)
#define NS_ITERS 9       // Newton-Schulz iterations for inv-sqrt
#define SWZ(i,j) (((i)<<4) + ((((i)+(j))&15)))   // conflict-free Jacobi layout

// Wave-private LDS sync: writes committed (lgkmcnt) + compiler fence.
// Valid because each wave only ever reads LDS written by ITSELF between syncs.
__device__ __forceinline__ void wave_sync(){
    asm volatile("s_waitcnt lgkmcnt(0)" ::: "memory");
    __builtin_amdgcn_sched_barrier(0);
}

// ---------------------------------------------------------------------------
// Wave-cooperative 16x16 matmul: C = A*B. Lane l computes row (l&15),
// columns [ (l>>4)*4 .. +3 ]. Caller handles syncs.
// ---------------------------------------------------------------------------
__device__ __forceinline__ void matmul16(const float* A, const float* B, float* C, int lane){
    int i  = lane & 15;
    int j0 = (lane >> 4) * 4;
    float c0 = 0.f, c1 = 0.f, c2 = 0.f, c3 = 0.f;
#pragma unroll
    for (int k = 0; k < 16; ++k){
        float a = A[i*LDM + k];
        c0 = fmaf(a, B[k*LDM + j0 + 0], c0);
        c1 = fmaf(a, B[k*LDM + j0 + 1], c1);
        c2 = fmaf(a, B[k*LDM + j0 + 2], c2);
        c3 = fmaf(a, B[k*LDM + j0 + 3], c3);
    }
    C[i*LDM + j0 + 0] = c0;
    C[i*LDM + j0 + 1] = c1;
    C[i*LDM + j0 + 2] = c2;
    C[i*LDM + j0 + 3] = c3;
}

// Tournament (circle-method) pairing: round r in [0,15), pair k in [0,8)
__device__ __forceinline__ void jpair(int r, int k, int& pI, int& qI){
    if (k == 0){ pI = r; qI = 15; }
    else {
        int a = (r + k) % 15;
        int b = (r + 15 - k) % 15;
        pI = a < b ? a : b;
        qI = a < b ? b : a;
    }
}

// ---------------------------------------------------------------------------
// Kernel 1: S_n = Y_n^{-1/2} for all n, via coupled Newton-Schulz.
// One wave per point, 4 points per block. (~1% of runtime — unchanged.)
// ---------------------------------------------------------------------------
__global__ __launch_bounds__(256) void precompute_invsqrt(const float* __restrict__ embeds,
                                                          float* __restrict__ Sout){
    __shared__ float buf[4][5][16*LDM];
    const int w    = threadIdx.x >> 6;
    const int lane = threadIdx.x & 63;
    const int n    = blockIdx.x * 4 + w;

    float* Bm = buf[w][0];
    float* Zm = buf[w][1];
    float* Tm = buf[w][2];
    float* B2 = buf[w][3];
    float* Z2 = buf[w][4];

    const float* gY = embeds + (size_t)n * 512 + 256;

    float ss = 0.f;
#pragma unroll
    for (int t = 0; t < 4; ++t){
        int e = lane + t*64;
        float v = gY[e];
        Bm[(e >> 4)*LDM + (e & 15)] = v;
        ss += v*v;
    }
#pragma unroll
    for (int m = 1; m < 64; m <<= 1) ss += __shfl_xor(ss, m);
    float f    = sqrtf(ss);
    float invf = 1.0f / f;
    __syncthreads();

#pragma unroll
    for (int t = 0; t < 4; ++t){
        int e = lane + t*64; int i = e >> 4, j = e & 15;
        Bm[i*LDM + j] *= invf;
        Zm[i*LDM + j]  = (i == j) ? 1.f : 0.f;
    }
    __syncthreads();

    for (int it = 0; it < NS_ITERS; ++it){
        matmul16(Zm, Bm, Tm, lane);
        __syncthreads();
#pragma unroll
        for (int t = 0; t < 4; ++t){
            int e = lane + t*64; int i = e >> 4, j = e & 15;
            float v = -0.5f * Tm[i*LDM + j] + ((i == j) ? 1.5f : 0.f);
            Tm[i*LDM + j] = v;
        }
        __syncthreads();
        matmul16(Bm, Tm, B2, lane);
        matmul16(Tm, Zm, Z2, lane);
        __syncthreads();
        float* tp;
        tp = Bm; Bm = B2; B2 = tp;
        tp = Zm; Zm = Z2; Z2 = tp;
    }

    float sc = rsqrtf(f);
    float* out = Sout + (size_t)n * 256;
#pragma unroll
    for (int t = 0; t < 4; ++t){
        int e = lane + t*64; int i = e >> 4, j = e & 15;
        out[e] = Zm[i*LDM + j] * sc;
    }
}

// ---------------------------------------------------------------------------
// Kernel 2: per-pair Siegel distance -> loss term. One wave per pair,
// fully wave-private (no block barriers in the hot path).
// ---------------------------------------------------------------------------
__global__ __launch_bounds__(256) void siegel_pairs(const float* __restrict__ embeds,
                                                    const float* __restrict__ gdist,
                                                    const int*   __restrict__ src,
                                                    const int*   __restrict__ dst,
                                                    const float* __restrict__ S,
                                                    float* __restrict__ partials,
                                                    int P){
    __shared__ float  buf[4][4][16*LDM];   // 4 matrices per wave
    __shared__ float4 rotv[4][8];
    __shared__ ushort ptab[120];           // tournament pair table (block-shared, RO)
    __shared__ float  wterm[4];

    const int w    = threadIdx.x >> 6;
    const int lane = threadIdx.x & 63;

    if (threadIdx.x < 120){
        int r = threadIdx.x >> 3, k = threadIdx.x & 7;
        int pI, qI; jpair(r, k, pI, qI);
        ptab[threadIdx.x] = (ushort)(pI | (qI << 8));
    }
    __syncthreads();                        // ptab ready for all waves

    const int p = blockIdx.x * 4 + w;
    const bool valid = (p < P);
    const int pp = valid ? p : 0;
    const int a = src[pp];
    const int b = dst[pp];

    float* M0 = buf[w][0];   // S2 -> E(CI, ldm layout)
    float* M1 = buf[w][1];   // Xd -> X3 -> (CRCI low half)
    float* M2 = buf[w][2];   // Y1 -> Y3 -> L -> (CRCI high half)
    float* M3 = buf[w][3];   // T1/T2 -> G(CR, ldm layout)
    float2* CRCI = (float2*)M1;  // 256 float2 spanning M1+M2 (dead by then)

    const float* e1 = embeds + (size_t)a * 512;
    const float* e2 = embeds + (size_t)b * 512;
    const float* S2 = S + (size_t)b * 256;

#pragma unroll
    for (int t = 0; t < 4; ++t){
        int e = lane + t*64; int i = e >> 4, j = e & 15;
        M0[i*LDM + j] = S2[e];
        M1[i*LDM + j] = e1[e] - e2[e];      // Xd = X1 - X2
        M2[i*LDM + j] = e1[256 + e];        // Y1
    }
    wave_sync();

    matmul16(M0, M1, M3, lane);             // T1 = S*Xd
    wave_sync();
    matmul16(M3, M0, M1, lane);             // X3 = T1*S   (over Xd)
    wave_sync();
    matmul16(M0, M2, M3, lane);             // T2 = S*Y1   (over T1)
    wave_sync();
    matmul16(M3, M0, M2, lane);             // Y3 = T2*S   (over Y1)
    wave_sync();

    // G = X3^2 + Y3^2 + I -> M3 ;  E = Y3*X3 - X3*Y3 -> M0   (H = G + iE)
    {
        int i = lane & 15, j0 = (lane >> 4) * 4;
        float g0=0,g1=0,g2=0,g3=0, q0=0,q1=0,q2=0,q3=0;
#pragma unroll
        for (int k = 0; k < 16; ++k){
            float x = M1[i*LDM + k];
            float y = M2[i*LDM + k];
            float xk0 = M1[k*LDM + j0+0], yk0 = M2[k*LDM + j0+0];
            float xk1 = M1[k*LDM + j0+1], yk1 = M2[k*LDM + j0+1];
            float xk2 = M1[k*LDM + j0+2], yk2 = M2[k*LDM + j0+2];
            float xk3 = M1[k*LDM + j0+3], yk3 = M2[k*LDM + j0+3];
            g0 += x*xk0 + y*yk0;  q0 += y*xk0 - x*yk0;
            g1 += x*xk1 + y*yk1;  q1 += y*xk1 - x*yk1;
            g2 += x*xk2 + y*yk2;  q2 += y*xk2 - x*yk2;
            g3 += x*xk3 + y*yk3;  q3 += y*xk3 - x*yk3;
        }
        M3[i*LDM + j0+0] = g0 + ((i == j0+0) ? 1.f : 0.f);
        M3[i*LDM + j0+1] = g1 + ((i == j0+1) ? 1.f : 0.f);
        M3[i*LDM + j0+2] = g2 + ((i == j0+2) ? 1.f : 0.f);
        M3[i*LDM + j0+3] = g3 + ((i == j0+3) ? 1.f : 0.f);
        M0[i*LDM + j0+0] = q0;
        M0[i*LDM + j0+1] = q1;
        M0[i*LDM + j0+2] = q2;
        M0[i*LDM + j0+3] = q3;
    }
    wave_sync();

    // Cholesky of Y3 (M2): L in lower triangle, 1/L_kk stored ON the diagonal
    for (int k = 0; k < 16; ++k){
        float akk = M2[k*LDM + k];
        float rs  = rsqrtf(akk);
        if (lane == 0) M2[k*LDM + k] = rs;
        if (lane > k && lane < 16) M2[lane*LDM + k] *= rs;
        wave_sync();
        int i = lane & 15, jg = lane >> 4;
        if (i > k){
            float lik = M2[i*LDM + k];
            for (int j = k + 1 + jg; j <= i; j += 4)
                M2[i*LDM + j] -= lik * M2[j*LDM + k];
        }
        wave_sync();
    }

    // Forward solve  Z = L^{-1} H : lanes 0-15 on G (M3), 16-31 on E (M0)
    {
        float* Mb = (lane < 16) ? M3 : ((lane < 32) ? M0 : (float*)0);
        int col = lane & 15;
        if (Mb){
            float z[16];
#pragma unroll
            for (int i = 0; i < 16; ++i){
                float v = Mb[i*LDM + col];
#pragma unroll
                for (int m = 0; m < i; ++m) v -= M2[i*LDM + m] * z[m];
                z[i] = v * M2[i*LDM + i];
            }
#pragma unroll
            for (int i = 0; i < 16; ++i) Mb[i*LDM + col] = z[i];
        }
    }
    wave_sync();

    // Row solve  C = Z L^{-T}
    {
        float* Mb = (lane < 16) ? M3 : ((lane < 32) ? M0 : (float*)0);
        int r = lane & 15;
        if (Mb){
            float z[16];
#pragma unroll
            for (int j = 0; j < 16; ++j){
                float v = Mb[r*LDM + j];
#pragma unroll
                for (int m = 0; m < j; ++m) v -= M2[j*LDM + m] * z[m];
                z[j] = v * M2[j*LDM + j];
            }
#pragma unroll
            for (int j = 0; j < 16; ++j) Mb[r*LDM + j] = z[j];
        }
    }
    wave_sync();

    // Hermitianize into interleaved, swizzled complex storage (over M1+M2)
    {
        int i = lane & 15, jg = lane >> 4;
#pragma unroll
        for (int t = 0; t < 4; ++t){
            int j = jg + 4*t;
            float cr = 0.5f*(M3[i*LDM + j] + M3[j*LDM + i]);
            float ci = 0.5f*(M0[i*LDM + j] - M0[j*LDM + i]);
            CRCI[SWZ(i,j)] = make_float2(cr, ci);
        }
    }
    wave_sync();

    // Jacobi, fused quad update: lane = k1*8 + k2 owns the 2x2 block
    // (rows {p1,q1} of pair k1) x (cols {p2,q2} of pair k2).
    const int k1 = lane >> 3, k2 = lane & 7;
#pragma unroll 1
    for (int sweep = 0; sweep < NSWEEP; ++sweep){
#pragma unroll 1
        for (int r = 0; r < 15; ++r){
            const ushort* pr = &ptab[r*8];
            if (lane < 8){
                int pq = pr[lane]; int pI = pq & 255, qI = pq >> 8;
                float app = CRCI[SWZ(pI,pI)].x;
                float aqq = CRCI[SWZ(qI,qI)].x;
                float2 bb = CRCI[SWZ(pI,qI)];
                float n2 = bb.x*bb.x + bb.y*bb.y;
                float c, s, wr, wi;
                if (n2 < 1e-28f){ c = 1.f; s = 0.f; wr = 1.f; wi = 0.f; }
                else {
                    float nb  = sqrtf(n2);
                    float inb = 1.0f / nb;
                    wr = bb.x * inb; wi = bb.y * inb;
                    float tau = (aqq - app) * (0.5f * inb);
                    float tt  = ((tau >= 0.f) ? 1.f : -1.f) / (fabsf(tau) + sqrtf(1.f + tau*tau));
                    c = rsqrtf(1.f + tt*tt);
                    s = tt * c;
                }
                rotv[w][lane] = make_float4(c, s, wr, wi);
            }
            wave_sync();

            int pq1 = pr[k1], pq2 = pr[k2];
            int p1 = pq1 & 255, q1 = pq1 >> 8;
            int p2 = pq2 & 255, q2 = pq2 >> 8;
            float4 r1 = rotv[w][k1];
            float4 r2 = rotv[w][k2];
            int aPP = SWZ(p1,p2), aPQ = SWZ(p1,q2);
            int aQP = SWZ(q1,p2), aQQ = SWZ(q1,q2);
            float2 a00 = CRCI[aPP], a01 = CRCI[aPQ];
            float2 a10 = CRCI[aQP], a11 = CRCI[aQQ];

            // left rotation (rows, pair k1):  wq = w1 * aq
            float w0r = r1.z*a10.x - r1.w*a10.y, w0i = r1.z*a10.y + r1.w*a10.x;
            float w1r = r1.z*a11.x - r1.w*a11.y, w1i = r1.z*a11.y + r1.w*a11.x;
            float b00x = r1.x*a00.x - r1.y*w0r,  b00y = r1.x*a00.y - r1.y*w0i;
            float b10x = r1.y*a00.x + r1.x*w0r,  b10y = r1.y*a00.y + r1.x*w0i;
            float b01x = r1.x*a01.x - r1.y*w1r,  b01y = r1.x*a01.y - r1.y*w1i;
            float b11x = r1.y*a01.x + r1.x*w1r,  b11y = r1.y*a01.y + r1.x*w1i;

            // right rotation (cols, pair k2):  wq = conj(w2) * aq
            float v0r = r2.z*b01x + r2.w*b01y,   v0i = r2.z*b01y - r2.w*b01x;
            float v1r = r2.z*b11x + r2.w*b11y,   v1i = r2.z*b11y - r2.w*b11x;
            CRCI[aPP] = make_float2(r2.x*b00x - r2.y*v0r, r2.x*b00y - r2.y*v0i);
            CRCI[aPQ] = make_float2(r2.y*b00x + r2.x*v0r, r2.y*b00y + r2.x*v0i);
            CRCI[aQP] = make_float2(r2.x*b10x - r2.y*v1r, r2.x*b10y - r2.y*v1i);
            CRCI[aQQ] = make_float2(r2.y*b10x + r2.x*v1r, r2.y*b10y + r2.x*v1i);
            wave_sync();
        }
    }

    // eigenvalues mu on diag -> lambda -> v -> sum v^2 -> loss term
    float t2 = 0.f;
    if (lane < 16){
        float mu  = CRCI[SWZ(lane,lane)].x;
        float lam = (mu - 2.f) / (mu + 2.f);
        const float lo = 1e-6f;
        const float hi = (1.f - 1e-6f) * (1.f - 1e-6f);
        lam = fminf(fmaxf(lam, lo), hi);
        float sv = sqrtf(lam);
        float v  = logf((1.f + sv) / (1.f - sv));
        t2 = v * v;
    }
#pragma unroll
    for (int m = 1; m < 16; m <<= 1) t2 += __shfl_xor(t2, m);
    if (lane == 0){
        float gd   = gdist[(size_t)a * NPTS + b];
        float term = fabsf(t2 / (gd * gd) - 1.f);
        wterm[w] = valid ? term : 0.f;
    }
    __syncthreads();
    if (threadIdx.x == 0)
        partials[blockIdx.x] = wterm[0] + wterm[1] + wterm[2] + wterm[3];
}

// ---------------------------------------------------------------------------
// Kernel 3: final reduction (double accumulation), single block
// ---------------------------------------------------------------------------
__global__ __launch_bounds__(256) void reduce_partials(const float* __restrict__ partials,
                                                       int n, float* __restrict__ out){
    __shared__ double sd[256];
    double s = 0.0;
    for (int i = threadIdx.x; i < n; i += 256) s += (double)partials[i];
    sd[threadIdx.x] = s;
    __syncthreads();
    for (int st = 128; st > 0; st >>= 1){
        if (threadIdx.x < st) sd[threadIdx.x] += sd[threadIdx.x + st];
        __syncthreads();
    }
    if (threadIdx.x == 0) out[0] = (float)sd[0];
}

extern "C" void kernel_launch(void* const* d_in, const int* in_sizes, int n_in,
                              void* d_out, int out_size, void* d_ws, size_t ws_size,
                              hipStream_t stream){
    const float* embeds = (const float*)d_in[0];
    const float* gdist  = (const float*)d_in[1];
    const int*   src    = (const int*)d_in[2];
    const int*   dst    = (const int*)d_in[3];
    const int P = in_sizes[2];

    float* S        = (float*)d_ws;                 // 2048*256 floats = 2 MB
    float* partials = S + (size_t)NPTS * 256;

    const int nb = (P + 3) / 4;

    precompute_invsqrt<<<dim3(NPTS/4), dim3(256), 0, stream>>>(embeds, S);
    siegel_pairs<<<dim3(nb), dim3(256), 0, stream>>>(embeds, gdist, src, dst, S, partials, P);
    reduce_partials<<<dim3(1), dim3(256), 0, stream>>>(partials, nb, (float*)d_out);
}

// Round 5
// 1204.534 us; speedup vs baseline: 3.0893x; 1.8480x over previous
//
#include <hip/hip_runtime.h>
#include <math.h>

#define NPTS 2048
#define LDM 17           // padded LDS row stride for the dense-matmul phase
#define MAXSWEEP 8       // Jacobi sweep cap (adaptive early exit from sweep 3)
#define NS_ITERS 9       // Newton-Schulz iterations for inv-sqrt
#define SWZ(i,j) (((i)<<4) + ((((i)+(j))&15)))   // Jacobi layout hash

// Wave-private LDS sync: writes committed (lgkmcnt) + compiler fence.
// Valid because each wave only ever reads LDS written by ITSELF between syncs.
__device__ __forceinline__ void wave_sync(){
    asm volatile("s_waitcnt lgkmcnt(0)" ::: "memory");
    __builtin_amdgcn_sched_barrier(0);
}

// ---------------------------------------------------------------------------
// Wave-cooperative 16x16 matmul: C = A*B. Lane l computes row (l&15),
// columns [ (l>>4)*4 .. +3 ]. Caller handles syncs.
// ---------------------------------------------------------------------------
__device__ __forceinline__ void matmul16(const float* A, const float* B, float* C, int lane){
    int i  = lane & 15;
    int j0 = (lane >> 4) * 4;
    float c0 = 0.f, c1 = 0.f, c2 = 0.f, c3 = 0.f;
#pragma unroll
    for (int k = 0; k < 16; ++k){
        float a = A[i*LDM + k];
        c0 = fmaf(a, B[k*LDM + j0 + 0], c0);
        c1 = fmaf(a, B[k*LDM + j0 + 1], c1);
        c2 = fmaf(a, B[k*LDM + j0 + 2], c2);
        c3 = fmaf(a, B[k*LDM + j0 + 3], c3);
    }
    C[i*LDM + j0 + 0] = c0;
    C[i*LDM + j0 + 1] = c1;
    C[i*LDM + j0 + 2] = c2;
    C[i*LDM + j0 + 3] = c3;
}

// Tournament (circle-method) pairing: round r in [0,15), pair k in [0,8)
__device__ __forceinline__ void jp(int r, int k, int& pI, int& qI){
    if (k == 0){ pI = r; qI = 15; }
    else {
        int a = r + k;      if (a >= 15) a -= 15;
        int b = r + 15 - k; if (b >= 15) b -= 15;
        pI = a < b ? a : b;
        qI = a < b ? b : a;
    }
}

// ---------------------------------------------------------------------------
// Kernel 1: S_n = Y_n^{-1/2} for all n, via coupled Newton-Schulz.
// One wave per point, 4 points per block. (~1% of runtime — unchanged.)
// ---------------------------------------------------------------------------
__global__ __launch_bounds__(256) void precompute_invsqrt(const float* __restrict__ embeds,
                                                          float* __restrict__ Sout){
    __shared__ float buf[4][5][16*LDM];
    const int w    = threadIdx.x >> 6;
    const int lane = threadIdx.x & 63;
    const int n    = blockIdx.x * 4 + w;

    float* Bm = buf[w][0];
    float* Zm = buf[w][1];
    float* Tm = buf[w][2];
    float* B2 = buf[w][3];
    float* Z2 = buf[w][4];

    const float* gY = embeds + (size_t)n * 512 + 256;

    float ss = 0.f;
#pragma unroll
    for (int t = 0; t < 4; ++t){
        int e = lane + t*64;
        float v = gY[e];
        Bm[(e >> 4)*LDM + (e & 15)] = v;
        ss += v*v;
    }
#pragma unroll
    for (int m = 1; m < 64; m <<= 1) ss += __shfl_xor(ss, m);
    float f    = sqrtf(ss);
    float invf = 1.0f / f;
    __syncthreads();

#pragma unroll
    for (int t = 0; t < 4; ++t){
        int e = lane + t*64; int i = e >> 4, j = e & 15;
        Bm[i*LDM + j] *= invf;
        Zm[i*LDM + j]  = (i == j) ? 1.f : 0.f;
    }
    __syncthreads();

    for (int it = 0; it < NS_ITERS; ++it){
        matmul16(Zm, Bm, Tm, lane);
        __syncthreads();
#pragma unroll
        for (int t = 0; t < 4; ++t){
            int e = lane + t*64; int i = e >> 4, j = e & 15;
            float v = -0.5f * Tm[i*LDM + j] + ((i == j) ? 1.5f : 0.f);
            Tm[i*LDM + j] = v;
        }
        __syncthreads();
        matmul16(Bm, Tm, B2, lane);
        matmul16(Tm, Zm, Z2, lane);
        __syncthreads();
        float* tp;
        tp = Bm; Bm = B2; B2 = tp;
        tp = Zm; Zm = Z2; Z2 = tp;
    }

    float sc = rsqrtf(f);
    float* out = Sout + (size_t)n * 256;
#pragma unroll
    for (int t = 0; t < 4; ++t){
        int e = lane + t*64; int i = e >> 4, j = e & 15;
        out[e] = Zm[i*LDM + j] * sc;
    }
}

// ---------------------------------------------------------------------------
// Kernel 2: per-pair Siegel distance -> loss term. One wave per pair,
// fully wave-private (no block barriers in the hot path).
// ---------------------------------------------------------------------------
__global__ __launch_bounds__(256) void siegel_pairs(const float* __restrict__ embeds,
                                                    const float* __restrict__ gdist,
                                                    const int*   __restrict__ src,
                                                    const int*   __restrict__ dst,
                                                    const float* __restrict__ S,
                                                    float* __restrict__ partials,
                                                    int P){
    __shared__ float  buf[4][4][16*LDM];   // 4 matrices per wave
    __shared__ float4 rotv[4][8];
    __shared__ float  wterm[4];

    const int w    = threadIdx.x >> 6;
    const int lane = threadIdx.x & 63;

    const int p = blockIdx.x * 4 + w;
    const bool valid = (p < P);
    const int pp = valid ? p : 0;
    const int a = src[pp];
    const int b = dst[pp];

    float* M0 = buf[w][0];   // S2 -> E(CI, ldm layout)
    float* M1 = buf[w][1];   // Xd -> X3 -> (CRCI low half)
    float* M2 = buf[w][2];   // Y1 -> Y3 -> L -> (CRCI high half)
    float* M3 = buf[w][3];   // T1/T2 -> G(CR, ldm layout)
    float2* CRCI = (float2*)M1;  // 256 float2 spanning M1+M2 (dead by then)

    const float* e1 = embeds + (size_t)a * 512;
    const float* e2 = embeds + (size_t)b * 512;
    const float* S2 = S + (size_t)b * 256;

#pragma unroll
    for (int t = 0; t < 4; ++t){
        int e = lane + t*64; int i = e >> 4, j = e & 15;
        M0[i*LDM + j] = S2[e];
        M1[i*LDM + j] = e1[e] - e2[e];      // Xd = X1 - X2
        M2[i*LDM + j] = e1[256 + e];        // Y1
    }
    wave_sync();

    matmul16(M0, M1, M3, lane);             // T1 = S*Xd
    wave_sync();
    matmul16(M3, M0, M1, lane);             // X3 = T1*S   (over Xd)
    wave_sync();
    matmul16(M0, M2, M3, lane);             // T2 = S*Y1   (over T1)
    wave_sync();
    matmul16(M3, M0, M2, lane);             // Y3 = T2*S   (over Y1)
    wave_sync();

    // G = X3^2 + Y3^2 + I -> M3 ;  E = Y3*X3 - X3*Y3 -> M0   (H = G + iE)
    {
        int i = lane & 15, j0 = (lane >> 4) * 4;
        float g0=0,g1=0,g2=0,g3=0, q0=0,q1=0,q2=0,q3=0;
#pragma unroll
        for (int k = 0; k < 16; ++k){
            float x = M1[i*LDM + k];
            float y = M2[i*LDM + k];
            float xk0 = M1[k*LDM + j0+0], yk0 = M2[k*LDM + j0+0];
            float xk1 = M1[k*LDM + j0+1], yk1 = M2[k*LDM + j0+1];
            float xk2 = M1[k*LDM + j0+2], yk2 = M2[k*LDM + j0+2];
            float xk3 = M1[k*LDM + j0+3], yk3 = M2[k*LDM + j0+3];
            g0 += x*xk0 + y*yk0;  q0 += y*xk0 - x*yk0;
            g1 += x*xk1 + y*yk1;  q1 += y*xk1 - x*yk1;
            g2 += x*xk2 + y*yk2;  q2 += y*xk2 - x*yk2;
            g3 += x*xk3 + y*yk3;  q3 += y*xk3 - x*yk3;
        }
        M3[i*LDM + j0+0] = g0 + ((i == j0+0) ? 1.f : 0.f);
        M3[i*LDM + j0+1] = g1 + ((i == j0+1) ? 1.f : 0.f);
        M3[i*LDM + j0+2] = g2 + ((i == j0+2) ? 1.f : 0.f);
        M3[i*LDM + j0+3] = g3 + ((i == j0+3) ? 1.f : 0.f);
        M0[i*LDM + j0+0] = q0;
        M0[i*LDM + j0+1] = q1;
        M0[i*LDM + j0+2] = q2;
        M0[i*LDM + j0+3] = q3;
    }
    wave_sync();

    // Cholesky of Y3 (M2): L in lower triangle, 1/L_kk stored ON the diagonal
    for (int k = 0; k < 16; ++k){
        float akk = M2[k*LDM + k];
        float rs  = rsqrtf(akk);
        if (lane == 0) M2[k*LDM + k] = rs;
        if (lane > k && lane < 16) M2[lane*LDM + k] *= rs;
        wave_sync();
        int i = lane & 15, jg = lane >> 4;
        if (i > k){
            float lik = M2[i*LDM + k];
            for (int j = k + 1 + jg; j <= i; j += 4)
                M2[i*LDM + j] -= lik * M2[j*LDM + k];
        }
        wave_sync();
    }

    // Forward solve  Z = L^{-1} H : lanes 0-15 on G (M3), 16-31 on E (M0)
    {
        float* Mb = (lane < 16) ? M3 : ((lane < 32) ? M0 : (float*)0);
        int col = lane & 15;
        if (Mb){
            float z[16];
#pragma unroll
            for (int i = 0; i < 16; ++i){
                float v = Mb[i*LDM + col];
#pragma unroll
                for (int m = 0; m < i; ++m) v -= M2[i*LDM + m] * z[m];
                z[i] = v * M2[i*LDM + i];
            }
#pragma unroll
            for (int i = 0; i < 16; ++i) Mb[i*LDM + col] = z[i];
        }
    }
    wave_sync();

    // Row solve  C = Z L^{-T}
    {
        float* Mb = (lane < 16) ? M3 : ((lane < 32) ? M0 : (float*)0);
        int r = lane & 15;
        if (Mb){
            float z[16];
#pragma unroll
            for (int j = 0; j < 16; ++j){
                float v = Mb[r*LDM + j];
#pragma unroll
                for (int m = 0; m < j; ++m) v -= M2[j*LDM + m] * z[m];
                z[j] = v * M2[j*LDM + j];
            }
#pragma unroll
            for (int j = 0; j < 16; ++j) Mb[r*LDM + j] = z[j];
        }
    }
    wave_sync();

    // Hermitianize into interleaved, swizzled complex storage (over M1+M2)
    {
        int i = lane & 15, jg = lane >> 4;
#pragma unroll
        for (int t = 0; t < 4; ++t){
            int j = jg + 4*t;
            float cr = 0.5f*(M3[i*LDM + j] + M3[j*LDM + i]);
            float ci = 0.5f*(M0[i*LDM + j] - M0[j*LDM + i]);
            CRCI[SWZ(i,j)] = make_float2(cr, ci);
        }
    }
    wave_sync();

    // Per-lane round tables: packed quad indices for all 15 rounds (regs).
    const int k1 = lane >> 3, k2 = lane & 7;
    const bool isdiag = (k1 == k2);
    unsigned qa[15];
#pragma unroll
    for (int r = 0; r < 15; ++r){
        int p1,q1,p2,q2;
        jp(r, k1, p1, q1);
        jp(r, k2, p2, q2);
        qa[r] = (unsigned)SWZ(p1,p2) | ((unsigned)SWZ(p1,q2) << 8)
              | ((unsigned)SWZ(q1,p2) << 16) | ((unsigned)SWZ(q1,q2) << 24);
    }

    // Jacobi, fused quad update; rotations on diagonal lanes (k1==k2).
    // J = [[c, sig],[-conj(sig), c]], sig = c*g*b, g = sgn(d)/(|d|+sqrt(d^2+|b|^2)),
    // c = rsqrt(1+|b|^2 g^2), d = (aqq-app)/2. Annihilates the pivot; unitary.
#pragma unroll 1
    for (int sweep = 0; sweep < MAXSWEEP; ++sweep){
#pragma unroll
        for (int r = 0; r < 15; ++r){
            unsigned q = qa[r];
            int iPP = q & 255, iPQ = (q >> 8) & 255, iQP = (q >> 16) & 255, iQQ = q >> 24;
            if (isdiag){
                float app = CRCI[iPP].x;
                float aqq = CRCI[iQQ].x;
                float2 bb = CRCI[iPQ];
                float n2 = bb.x*bb.x + bb.y*bb.y;
                float dd = 0.5f*(aqq - app);
                float h  = sqrtf(fmaf(dd, dd, n2));
                float den = fabsf(dd) + h + 1e-38f;
                float g  = 1.0f/den;
                g = (dd < 0.f) ? -g : g;
                float tt = (n2*g)*g;
                float c  = rsqrtf(1.f + tt);
                float cg = c*g;
                rotv[w][k1] = make_float4(c, cg*bb.x, cg*bb.y, 0.f);
            }
            wave_sync();

            float4 r1 = rotv[w][k1];
            float4 r2 = rotv[w][k2];
            float2 a00 = CRCI[iPP], a01 = CRCI[iPQ];
            float2 a10 = CRCI[iQP], a11 = CRCI[iQQ];

            // left: rows <- J1^H * rows
            float t0x = r1.y*a10.x - r1.z*a10.y, t0y = r1.y*a10.y + r1.z*a10.x; // sig1*a10
            float t1x = r1.y*a11.x - r1.z*a11.y, t1y = r1.y*a11.y + r1.z*a11.x; // sig1*a11
            float u0x = r1.y*a00.x + r1.z*a00.y, u0y = r1.y*a00.y - r1.z*a00.x; // conj(sig1)*a00
            float u1x = r1.y*a01.x + r1.z*a01.y, u1y = r1.y*a01.y - r1.z*a01.x; // conj(sig1)*a01
            float b00x = fmaf(r1.x, a00.x, -t0x), b00y = fmaf(r1.x, a00.y, -t0y);
            float b01x = fmaf(r1.x, a01.x, -t1x), b01y = fmaf(r1.x, a01.y, -t1y);
            float b10x = fmaf(r1.x, a10.x,  u0x), b10y = fmaf(r1.x, a10.y,  u0y);
            float b11x = fmaf(r1.x, a11.x,  u1x), b11y = fmaf(r1.x, a11.y,  u1y);

            // right: cols <- cols * J2
            float v0x = r2.y*b01x + r2.z*b01y, v0y = r2.y*b01y - r2.z*b01x;     // conj(sig2)*b01
            float w0x = r2.y*b00x - r2.z*b00y, w0y = r2.y*b00y + r2.z*b00x;     // sig2*b00
            float v1x = r2.y*b11x + r2.z*b11y, v1y = r2.y*b11y - r2.z*b11x;     // conj(sig2)*b11
            float w1x = r2.y*b10x - r2.z*b10y, w1y = r2.y*b10y + r2.z*b10x;     // sig2*b10
            CRCI[iPP] = make_float2(fmaf(r2.x, b00x, -v0x), fmaf(r2.x, b00y, -v0y));
            CRCI[iPQ] = make_float2(fmaf(r2.x, b01x,  w0x), fmaf(r2.x, b01y,  w0y));
            CRCI[iQP] = make_float2(fmaf(r2.x, b10x, -v1x), fmaf(r2.x, b10y, -v1y));
            CRCI[iQQ] = make_float2(fmaf(r2.x, b11x,  w1x), fmaf(r2.x, b11y,  w1y));
            wave_sync();
        }

        // Adaptive exit: off-diag Frobenius^2 vs total, fp32-floor threshold.
        if (sweep >= 2 && sweep < MAXSWEEP-1){
            float o2 = 0.f, s2 = 0.f;
#pragma unroll
            for (int t = 0; t < 4; ++t){
                int e = lane + t*64; int i = e >> 4, j = e & 15;
                float2 v = CRCI[SWZ(i,j)];
                float m = v.x*v.x + v.y*v.y;
                s2 += m;
                if (i != j) o2 += m;
            }
#pragma unroll
            for (int m = 1; m < 64; m <<= 1){
                o2 += __shfl_xor(o2, m);
                s2 += __shfl_xor(s2, m);
            }
            if (o2 <= 1.6e-11f * s2) break;
        }
    }

    // eigenvalues mu on diag -> lambda -> v -> sum v^2 -> loss term
    float t2 = 0.f;
    if (lane < 16){
        float mu  = CRCI[SWZ(lane,lane)].x;
        float lam = (mu - 2.f) / (mu + 2.f);
        const float lo = 1e-6f;
        const float hi = (1.f - 1e-6f) * (1.f - 1e-6f);
        lam = fminf(fmaxf(lam, lo), hi);
        float sv = sqrtf(lam);
        float v  = logf((1.f + sv) / (1.f - sv));
        t2 = v * v;
    }
#pragma unroll
    for (int m = 1; m < 16; m <<= 1) t2 += __shfl_xor(t2, m);
    if (lane == 0){
        float gd   = gdist[(size_t)a * NPTS + b];
        float term = fabsf(t2 / (gd * gd) - 1.f);
        wterm[w] = valid ? term : 0.f;
    }
    __syncthreads();
    if (threadIdx.x == 0)
        partials[blockIdx.x] = wterm[0] + wterm[1] + wterm[2] + wterm[3];
}

// ---------------------------------------------------------------------------
// Kernel 3: final reduction (double accumulation), single block
// ---------------------------------------------------------------------------
__global__ __launch_bounds__(256) void reduce_partials(const float* __restrict__ partials,
                                                       int n, float* __restrict__ out){
    __shared__ double sd[256];
    double s = 0.0;
    for (int i = threadIdx.x; i < n; i += 256) s += (double)partials[i];
    sd[threadIdx.x] = s;
    __syncthreads();
    for (int st = 128; st > 0; st >>= 1){
        if (threadIdx.x < st) sd[threadIdx.x] += sd[threadIdx.x + st];
        __syncthreads();
    }
    if (threadIdx.x == 0) out[0] = (float)sd[0];
}

extern "C" void kernel_launch(void* const* d_in, const int* in_sizes, int n_in,
                              void* d_out, int out_size, void* d_ws, size_t ws_size,
                              hipStream_t stream){
    const float* embeds = (const float*)d_in[0];
    const float* gdist  = (const float*)d_in[1];
    const int*   src    = (const int*)d_in[2];
    const int*   dst    = (const int*)d_in[3];
    const int P = in_sizes[2];

    float* S        = (float*)d_ws;                 // 2048*256 floats = 2 MB
    float* partials = S + (size_t)NPTS * 256;

    const int nb = (P + 3) / 4;

    precompute_invsqrt<<<dim3(NPTS/4), dim3(256), 0, stream>>>(embeds, S);
    siegel_pairs<<<dim3(nb), dim3(256), 0, stream>>>(embeds, gdist, src, dst, S, partials, P);
    reduce_partials<<<dim3(1), dim3(256), 0, stream>>>(partials, nb, (float*)d_out);
}

// Round 6
// 1120.074 us; speedup vs baseline: 3.3223x; 1.0754x over previous
//
#include <hip/hip_runtime.h>
#include <math.h>

#define NPTS 2048
#define LDM 20           // padded LDS row stride: 80B rows -> 16B-aligned b128,
                         // col-reads 2-way bank-aliased (free per m136)
#define MAXSWEEP 8       // Jacobi sweep cap (adaptive early exit from sweep 3)
#define NS_ITERS 9       // Newton-Schulz iterations for inv-sqrt
#define SWZ(i,j) (((i)<<4) + ((((i)+(j))&15)))   // Jacobi layout hash

// Wave-private LDS sync: writes committed (lgkmcnt) + compiler fence.
// Valid because each wave only ever reads LDS written by ITSELF between syncs.
__device__ __forceinline__ void wave_sync(){
    asm volatile("s_waitcnt lgkmcnt(0)" ::: "memory");
    __builtin_amdgcn_sched_barrier(0);
}

// ---------------------------------------------------------------------------
// Wave-cooperative 16x16 matmul: C = A*B. Lane l computes row (l&15),
// columns [ (l>>4)*4 .. +3 ]. B-row reads and C-write are b128.
// ---------------------------------------------------------------------------
__device__ __forceinline__ void matmul16(const float* A, const float* B, float* C, int lane){
    int i  = lane & 15;
    int j0 = (lane >> 4) * 4;
    float c0 = 0.f, c1 = 0.f, c2 = 0.f, c3 = 0.f;
#pragma unroll
    for (int k = 0; k < 16; ++k){
        float a = A[i*LDM + k];
        float4 b = *reinterpret_cast<const float4*>(&B[k*LDM + j0]);
        c0 = fmaf(a, b.x, c0);
        c1 = fmaf(a, b.y, c1);
        c2 = fmaf(a, b.z, c2);
        c3 = fmaf(a, b.w, c3);
    }
    *reinterpret_cast<float4*>(&C[i*LDM + j0]) = make_float4(c0, c1, c2, c3);
}

// Tournament (circle-method) pairing: round r in [0,15), pair k in [0,8)
__device__ __forceinline__ void jp(int r, int k, int& pI, int& qI){
    if (k == 0){ pI = r; qI = 15; }
    else {
        int a = r + k;      if (a >= 15) a -= 15;
        int b = r + 15 - k; if (b >= 15) b -= 15;
        pI = a < b ? a : b;
        qI = a < b ? b : a;
    }
}

// ---------------------------------------------------------------------------
// Kernel 1: S_n = Y_n^{-1/2} for all n, via coupled Newton-Schulz.
// One wave per point, 4 points per block. (~1% of runtime.)
// ---------------------------------------------------------------------------
__global__ __launch_bounds__(256) void precompute_invsqrt(const float* __restrict__ embeds,
                                                          float* __restrict__ Sout){
    __shared__ __attribute__((aligned(16))) float buf[4][5][16*LDM];
    const int w    = threadIdx.x >> 6;
    const int lane = threadIdx.x & 63;
    const int n    = blockIdx.x * 4 + w;

    float* Bm = buf[w][0];
    float* Zm = buf[w][1];
    float* Tm = buf[w][2];
    float* B2 = buf[w][3];
    float* Z2 = buf[w][4];

    const float* gY = embeds + (size_t)n * 512 + 256;

    float ss = 0.f;
#pragma unroll
    for (int t = 0; t < 4; ++t){
        int e = lane + t*64;
        float v = gY[e];
        Bm[(e >> 4)*LDM + (e & 15)] = v;
        ss += v*v;
    }
#pragma unroll
    for (int m = 1; m < 64; m <<= 1) ss += __shfl_xor(ss, m);
    float f    = sqrtf(ss);
    float invf = 1.0f / f;
    __syncthreads();

#pragma unroll
    for (int t = 0; t < 4; ++t){
        int e = lane + t*64; int i = e >> 4, j = e & 15;
        Bm[i*LDM + j] *= invf;
        Zm[i*LDM + j]  = (i == j) ? 1.f : 0.f;
    }
    __syncthreads();

    for (int it = 0; it < NS_ITERS; ++it){
        matmul16(Zm, Bm, Tm, lane);
        __syncthreads();
#pragma unroll
        for (int t = 0; t < 4; ++t){
            int e = lane + t*64; int i = e >> 4, j = e & 15;
            float v = -0.5f * Tm[i*LDM + j] + ((i == j) ? 1.5f : 0.f);
            Tm[i*LDM + j] = v;
        }
        __syncthreads();
        matmul16(Bm, Tm, B2, lane);
        matmul16(Tm, Zm, Z2, lane);
        __syncthreads();
        float* tp;
        tp = Bm; Bm = B2; B2 = tp;
        tp = Zm; Zm = Z2; Z2 = tp;
    }

    float sc = rsqrtf(f);
    float* out = Sout + (size_t)n * 256;
#pragma unroll
    for (int t = 0; t < 4; ++t){
        int e = lane + t*64; int i = e >> 4, j = e & 15;
        out[e] = Zm[i*LDM + j] * sc;
    }
}

// ---------------------------------------------------------------------------
// Kernel 2: per-pair Siegel distance -> loss term. One wave per pair,
// fully wave-private (no block barriers in the hot path).
// ---------------------------------------------------------------------------
__global__ __launch_bounds__(256) void siegel_pairs(const float* __restrict__ embeds,
                                                    const float* __restrict__ gdist,
                                                    const int*   __restrict__ src,
                                                    const int*   __restrict__ dst,
                                                    const float* __restrict__ S,
                                                    float* __restrict__ partials,
                                                    int P){
    __shared__ __attribute__((aligned(16))) float buf[4][4][16*LDM];
    __shared__ float wterm[4];

    const int w    = threadIdx.x >> 6;
    const int lane = threadIdx.x & 63;

    const int p = blockIdx.x * 4 + w;
    const bool valid = (p < P);
    const int pp = valid ? p : 0;
    const int a = src[pp];
    const int b = dst[pp];

    float* M0 = buf[w][0];   // S2 -> E(CI, ldm layout)
    float* M1 = buf[w][1];   // Xd -> X3 -> (CRCI low half)
    float* M2 = buf[w][2];   // Y1 -> Y3 -> L -> (CRCI high half)
    float* M3 = buf[w][3];   // T1/T2 -> G(CR, ldm layout)
    float2* CRCI = (float2*)M1;  // 256 float2 spanning M1+M2 (dead by then)

    const float4* e1v = reinterpret_cast<const float4*>(embeds + (size_t)a * 512);
    const float4* e2v = reinterpret_cast<const float4*>(embeds + (size_t)b * 512);
    const float4* S2v = reinterpret_cast<const float4*>(S + (size_t)b * 256);

    // Staging: float4 global loads, b128 LDS stores (row = lane>>2, col = 4*(lane&3))
    {
        int row = lane >> 2, c4 = (lane & 3) * 4;
        float4 sv = S2v[lane];
        float4 x1 = e1v[lane];
        float4 x2 = e2v[lane];
        float4 y1 = e1v[64 + lane];
        *reinterpret_cast<float4*>(&M0[row*LDM + c4]) = sv;
        *reinterpret_cast<float4*>(&M1[row*LDM + c4]) =
            make_float4(x1.x - x2.x, x1.y - x2.y, x1.z - x2.z, x1.w - x2.w);
        *reinterpret_cast<float4*>(&M2[row*LDM + c4]) = y1;
    }
    wave_sync();

    matmul16(M0, M1, M3, lane);             // T1 = S*Xd
    wave_sync();
    matmul16(M3, M0, M1, lane);             // X3 = T1*S   (over Xd)
    wave_sync();
    matmul16(M0, M2, M3, lane);             // T2 = S*Y1   (over T1)
    wave_sync();
    matmul16(M3, M0, M2, lane);             // Y3 = T2*S   (over Y1)
    wave_sync();

    // G = X3^2 + Y3^2 + I -> M3 ;  E = Y3*X3 - X3*Y3 -> M0   (H = G + iE)
    {
        int i = lane & 15, j0 = (lane >> 4) * 4;
        float g0=0,g1=0,g2=0,g3=0, q0=0,q1=0,q2=0,q3=0;
#pragma unroll
        for (int k = 0; k < 16; ++k){
            float x = M1[i*LDM + k];
            float y = M2[i*LDM + k];
            float4 xk = *reinterpret_cast<const float4*>(&M1[k*LDM + j0]);
            float4 yk = *reinterpret_cast<const float4*>(&M2[k*LDM + j0]);
            g0 += x*xk.x + y*yk.x;  q0 += y*xk.x - x*yk.x;
            g1 += x*xk.y + y*yk.y;  q1 += y*xk.y - x*yk.y;
            g2 += x*xk.z + y*yk.z;  q2 += y*xk.z - x*yk.z;
            g3 += x*xk.w + y*yk.w;  q3 += y*xk.w - x*yk.w;
        }
        *reinterpret_cast<float4*>(&M3[i*LDM + j0]) = make_float4(
            g0 + ((i == j0+0) ? 1.f : 0.f),
            g1 + ((i == j0+1) ? 1.f : 0.f),
            g2 + ((i == j0+2) ? 1.f : 0.f),
            g3 + ((i == j0+3) ? 1.f : 0.f));
        *reinterpret_cast<float4*>(&M0[i*LDM + j0]) = make_float4(q0, q1, q2, q3);
    }
    wave_sync();

    // Cholesky of Y3 (M2): L in lower triangle, 1/L_kk stored ON the diagonal
    for (int k = 0; k < 16; ++k){
        float akk = M2[k*LDM + k];
        float rs  = rsqrtf(akk);
        if (lane == 0) M2[k*LDM + k] = rs;
        if (lane > k && lane < 16) M2[lane*LDM + k] *= rs;
        wave_sync();
        int i = lane & 15, jg = lane >> 4;
        if (i > k){
            float lik = M2[i*LDM + k];
            for (int j = k + 1 + jg; j <= i; j += 4)
                M2[i*LDM + j] -= lik * M2[j*LDM + k];
        }
        wave_sync();
    }

    // Forward solve  Z = L^{-1} H : lanes 0-15 on G (M3), 16-31 on E (M0)
    {
        float* Mb = (lane < 16) ? M3 : ((lane < 32) ? M0 : (float*)0);
        int col = lane & 15;
        if (Mb){
            float z[16];
#pragma unroll
            for (int i = 0; i < 16; ++i){
                float v = Mb[i*LDM + col];
#pragma unroll
                for (int m = 0; m < i; ++m) v -= M2[i*LDM + m] * z[m];
                z[i] = v * M2[i*LDM + i];
            }
#pragma unroll
            for (int i = 0; i < 16; ++i) Mb[i*LDM + col] = z[i];
        }
    }
    wave_sync();

    // Row solve  C = Z L^{-T}
    {
        float* Mb = (lane < 16) ? M3 : ((lane < 32) ? M0 : (float*)0);
        int r = lane & 15;
        if (Mb){
            float z[16];
#pragma unroll
            for (int j = 0; j < 16; ++j){
                float v = Mb[r*LDM + j];
#pragma unroll
                for (int m = 0; m < j; ++m) v -= M2[j*LDM + m] * z[m];
                z[j] = v * M2[j*LDM + j];
            }
#pragma unroll
            for (int j = 0; j < 16; ++j) Mb[r*LDM + j] = z[j];
        }
    }
    wave_sync();

    // Hermitianize into interleaved, swizzled complex storage (over M1+M2)
    {
        int i = lane & 15, jg = lane >> 4;
#pragma unroll
        for (int t = 0; t < 4; ++t){
            int j = jg + 4*t;
            float cr = 0.5f*(M3[i*LDM + j] + M3[j*LDM + i]);
            float ci = 0.5f*(M0[i*LDM + j] - M0[j*LDM + i]);
            CRCI[SWZ(i,j)] = make_float2(cr, ci);
        }
    }
    wave_sync();

    // Per-lane round tables: packed quad indices for all 15 rounds (regs).
    const int k1 = lane >> 3, k2 = lane & 7;
    const bool isdiag = (k1 == k2);
    const int d1 = 9*k1, d2 = 9*k2;     // diag-lane ids holding rot(k1), rot(k2)
    unsigned qa[15];
#pragma unroll
    for (int r = 0; r < 15; ++r){
        int p1,q1,p2,q2;
        jp(r, k1, p1, q1);
        jp(r, k2, p2, q2);
        qa[r] = (unsigned)SWZ(p1,p2) | ((unsigned)SWZ(p1,q2) << 8)
              | ((unsigned)SWZ(q1,p2) << 16) | ((unsigned)SWZ(q1,q2) << 24);
    }

    // Jacobi, fused quad update. Rotations computed on diagonal lanes FROM
    // THEIR OWN QUAD REGISTERS (a00.x=app, a01=b, a11.x=aqq), broadcast via
    // shuffles — no LDS round-trip, one sync per round.
    float off2 = 0.f, tot2 = 0.f;
#pragma unroll 1
    for (int sweep = 0; sweep < MAXSWEEP; ++sweep){
#pragma unroll
        for (int r = 0; r < 15; ++r){
            unsigned q = qa[r];
            int iPP = q & 255, iPQ = (q >> 8) & 255, iQP = (q >> 16) & 255, iQQ = q >> 24;
            float2 a00 = CRCI[iPP], a01 = CRCI[iPQ];
            float2 a10 = CRCI[iQP], a11 = CRCI[iQQ];

            float rc = 1.f, rsx = 0.f, rsy = 0.f;
            if (isdiag){
                float n2 = a01.x*a01.x + a01.y*a01.y;
                float dd = 0.5f*(a11.x - a00.x);
                float h  = sqrtf(fmaf(dd, dd, n2));
                float den = fabsf(dd) + h + 1e-38f;
                float g  = 1.0f/den;
                g = (dd < 0.f) ? -g : g;
                float tt = (n2*g)*g;
                rc  = rsqrtf(1.f + tt);
                float cg = rc*g;
                rsx = cg*a01.x; rsy = cg*a01.y;
            }
            float r1x = __shfl(rc, d1), r1y = __shfl(rsx, d1), r1z = __shfl(rsy, d1);
            float r2x = __shfl(rc, d2), r2y = __shfl(rsx, d2), r2z = __shfl(rsy, d2);

            // left: rows <- J1^H * rows
            float t0x = r1y*a10.x - r1z*a10.y, t0y = r1y*a10.y + r1z*a10.x; // sig1*a10
            float t1x = r1y*a11.x - r1z*a11.y, t1y = r1y*a11.y + r1z*a11.x; // sig1*a11
            float u0x = r1y*a00.x + r1z*a00.y, u0y = r1y*a00.y - r1z*a00.x; // conj(sig1)*a00
            float u1x = r1y*a01.x + r1z*a01.y, u1y = r1y*a01.y - r1z*a01.x; // conj(sig1)*a01
            float b00x = fmaf(r1x, a00.x, -t0x), b00y = fmaf(r1x, a00.y, -t0y);
            float b01x = fmaf(r1x, a01.x, -t1x), b01y = fmaf(r1x, a01.y, -t1y);
            float b10x = fmaf(r1x, a10.x,  u0x), b10y = fmaf(r1x, a10.y,  u0y);
            float b11x = fmaf(r1x, a11.x,  u1x), b11y = fmaf(r1x, a11.y,  u1y);

            // right: cols <- cols * J2
            float v0x = r2y*b01x + r2z*b01y, v0y = r2y*b01y - r2z*b01x;     // conj(sig2)*b01
            float w0x = r2y*b00x - r2z*b00y, w0y = r2y*b00y + r2z*b00x;     // sig2*b00
            float v1x = r2y*b11x + r2z*b11y, v1y = r2y*b11y - r2z*b11x;     // conj(sig2)*b11
            float w1x = r2y*b10x - r2z*b10y, w1y = r2y*b10y + r2z*b10x;     // sig2*b10
            float n00x = fmaf(r2x, b00x, -v0x), n00y = fmaf(r2x, b00y, -v0y);
            float n01x = fmaf(r2x, b01x,  w0x), n01y = fmaf(r2x, b01y,  w0y);
            float n10x = fmaf(r2x, b10x, -v1x), n10y = fmaf(r2x, b10y, -v1y);
            float n11x = fmaf(r2x, b11x,  w1x), n11y = fmaf(r2x, b11y,  w1y);
            CRCI[iPP] = make_float2(n00x, n00y);
            CRCI[iPQ] = make_float2(n01x, n01y);
            CRCI[iQP] = make_float2(n10x, n10y);
            CRCI[iQQ] = make_float2(n11x, n11y);

            if (r == 14){   // in-register convergence data (matrix covered once)
                float mPP = n00x*n00x + n00y*n00y;
                float mPQ = n01x*n01x + n01y*n01y;
                float mQP = n10x*n10x + n10y*n10y;
                float mQQ = n11x*n11x + n11y*n11y;
                tot2 = mPP + mPQ + mQP + mQQ;
                off2 = isdiag ? (mPQ + mQP) : tot2;
            }
            wave_sync();
        }

        // Adaptive exit: off-diag Frobenius^2 vs total, fp32-floor threshold.
        if (sweep >= 2 && sweep < MAXSWEEP-1){
            float o2 = off2, s2 = tot2;
#pragma unroll
            for (int m = 1; m < 64; m <<= 1){
                o2 += __shfl_xor(o2, m);
                s2 += __shfl_xor(s2, m);
            }
            if (o2 <= 1.6e-11f * s2) break;
        }
    }
    wave_sync();

    // eigenvalues mu on diag -> lambda -> v -> sum v^2 -> loss term
    float t2 = 0.f;
    if (lane < 16){
        float mu  = CRCI[SWZ(lane,lane)].x;
        float lam = (mu - 2.f) / (mu + 2.f);
        const float lo = 1e-6f;
        const float hi = (1.f - 1e-6f) * (1.f - 1e-6f);
        lam = fminf(fmaxf(lam, lo), hi);
        float sv = sqrtf(lam);
        float v  = logf((1.f + sv) / (1.f - sv));
        t2 = v * v;
    }
#pragma unroll
    for (int m = 1; m < 16; m <<= 1) t2 += __shfl_xor(t2, m);
    if (lane == 0){
        float gd   = gdist[(size_t)a * NPTS + b];
        float term = fabsf(t2 / (gd * gd) - 1.f);
        wterm[w] = valid ? term : 0.f;
    }
    __syncthreads();
    if (threadIdx.x == 0)
        partials[blockIdx.x] = wterm[0] + wterm[1] + wterm[2] + wterm[3];
}

// ---------------------------------------------------------------------------
// Kernel 3: final reduction (double accumulation), single block
// ---------------------------------------------------------------------------
__global__ __launch_bounds__(256) void reduce_partials(const float* __restrict__ partials,
                                                       int n, float* __restrict__ out){
    __shared__ double sd[256];
    double s = 0.0;
    for (int i = threadIdx.x; i < n; i += 256) s += (double)partials[i];
    sd[threadIdx.x] = s;
    __syncthreads();
    for (int st = 128; st > 0; st >>= 1){
        if (threadIdx.x < st) sd[threadIdx.x] += sd[threadIdx.x + st];
        __syncthreads();
    }
    if (threadIdx.x == 0) out[0] = (float)sd[0];
}

extern "C" void kernel_launch(void* const* d_in, const int* in_sizes, int n_in,
                              void* d_out, int out_size, void* d_ws, size_t ws_size,
                              hipStream_t stream){
    const float* embeds = (const float*)d_in[0];
    const float* gdist  = (const float*)d_in[1];
    const int*   src    = (const int*)d_in[2];
    const int*   dst    = (const int*)d_in[3];
    const int P = in_sizes[2];

    float* S        = (float*)d_ws;                 // 2048*256 floats = 2 MB
    float* partials = S + (size_t)NPTS * 256;

    const int nb = (P + 3) / 4;

    precompute_invsqrt<<<dim3(NPTS/4), dim3(256), 0, stream>>>(embeds, S);
    siegel_pairs<<<dim3(nb), dim3(256), 0, stream>>>(embeds, gdist, src, dst, S, partials, P);
    reduce_partials<<<dim3(1), dim3(256), 0, stream>>>(partials, nb, (float*)d_out);
}